// Round 9
// baseline (309.219 us; speedup 1.0000x reference)
//
#include <hip/hip_runtime.h>

#define Bb 8
#define Nn 1025
#define Hh 12
#define HD 64
#define DIMC 768
#define QKVC 2304          // 3*DIMC, token stride of packed qkv
#define MROWS (Bb * Nn)    // 8200
#define MPADA 8320         // 65*128, padded A rows for unguarded global_load_lds staging
#define NPAD 1152          // 18*64, zero-padded token dim for transposed V
#define K1 0.180336880111f // 0.125 * log2(e) — folded into q by rope kernel
#define PADCNT 127.0f      // 9*128 - 1025 pad tokens, each contributing p=2^0=1 to l

typedef _Float16 f16x8 __attribute__((ext_vector_type(8)));
typedef _Float16 f16x4 __attribute__((ext_vector_type(4)));
typedef _Float16 f16x2 __attribute__((ext_vector_type(2)));
typedef float f32x4 __attribute__((ext_vector_type(4)));
typedef int i32x4 __attribute__((ext_vector_type(4)));

typedef const __attribute__((address_space(1))) void gv_t;
typedef __attribute__((address_space(3))) void lv_t;

// ---------------- fused fp32 -> fp16 convert for 3 tensors ----------------
__global__ void cvt3_kernel(const float* __restrict__ s0, _Float16* __restrict__ d0, int n0,
                            const float* __restrict__ s1, _Float16* __restrict__ d1, int n1,
                            const float* __restrict__ s2, _Float16* __restrict__ d2, int n2) {
    int i = blockIdx.x * 256 + threadIdx.x;
    const float* s; _Float16* d; int j;
    if (i < n0)           { s = s0; d = d0; j = i; }
    else if (i < n0 + n1) { s = s1; d = d1; j = i - n0; }
    else if (i < n0 + n1 + n2) { s = s2; d = d2; j = i - n0 - n1; }
    else return;
    float4 v = ((const float4*)s)[j];
    f16x4 h;
    h.x = (_Float16)v.x; h.y = (_Float16)v.y; h.z = (_Float16)v.z; h.w = (_Float16)v.w;
    ((f16x4*)d)[j] = h;
}

// ---------------- MFMA GEMM, global_load_lds staging, 2xBK=32 per barrier ----------------
// Two slot-layout buffers staged together -> one barrier pair per 64 K-elems
// (halves barrier-drain count vs R7/R8). Slot layout unchanged (pad-free, 2-way-free).
template <int MODE>
__global__ void __launch_bounds__(256) gemm_kernel(
    const _Float16* __restrict__ A, const _Float16* __restrict__ W,
    int M, int Ncols, int K,
    _Float16* __restrict__ outh, const float* __restrict__ bias, float* __restrict__ outf)
{
    __shared__ _Float16 As[2][128 * 32];
    __shared__ _Float16 Ws[2][128 * 32];
    const int tid = threadIdx.x;
    const int wid = tid >> 6, lane = tid & 63;
    const int quad = lane >> 4, l16 = lane & 15;
    const int bm = blockIdx.x * 128, bn = blockIdx.y * 128;
    const int wm = (wid >> 1) * 64, wn = (wid & 1) * 64;

    f32x4 acc[4][4] = {};

    for (int kk = 0; kk < K; kk += 64) {
#pragma unroll
        for (int half = 0; half < 2; ++half) {
#pragma unroll
            for (int c = 0; c < 2; ++c) {
                int s = c * 256 + tid;
                int row = s >> 2, gr = s & 3;
                const _Float16* ga = A + (size_t)(bm + row) * K + kk + half * 32 + gr * 8;
                const _Float16* gw = W + (size_t)(bn + row) * K + kk + half * 32 + gr * 8;
                _Float16* la = As[half] + (size_t)(c * 256 + wid * 64) * 8;
                _Float16* lw = Ws[half] + (size_t)(c * 256 + wid * 64) * 8;
                __builtin_amdgcn_global_load_lds((gv_t*)ga, (lv_t*)la, 16, 0, 0);
                __builtin_amdgcn_global_load_lds((gv_t*)gw, (lv_t*)lw, 16, 0, 0);
            }
        }
        __syncthreads();

#pragma unroll
        for (int half = 0; half < 2; ++half) {
            f16x8 af[4], bf[4];
#pragma unroll
            for (int t = 0; t < 4; ++t) {
                af[t] = *(const f16x8*)(As[half] + (size_t)(wm + t * 16 + l16) * 32 + quad * 8);
                bf[t] = *(const f16x8*)(Ws[half] + (size_t)(wn + t * 16 + l16) * 32 + quad * 8);
            }
#pragma unroll
            for (int tm = 0; tm < 4; ++tm)
#pragma unroll
                for (int tn = 0; tn < 4; ++tn)
                    acc[tm][tn] = __builtin_amdgcn_mfma_f32_16x16x32_f16(af[tm], bf[tn], acc[tm][tn], 0, 0, 0);
        }
        __syncthreads();
    }

#pragma unroll
    for (int tm = 0; tm < 4; ++tm) {
#pragma unroll
        for (int r = 0; r < 4; ++r) {
            int row = bm + wm + tm * 16 + quad * 4 + r;
            if (row >= M) continue;
#pragma unroll
            for (int tn = 0; tn < 4; ++tn) {
                int col = bn + wn + tn * 16 + l16;
                float val = acc[tm][tn][r];
                if (MODE == 0) {
                    outh[(size_t)row * Ncols + col] = (_Float16)val;
                } else {
                    outf[(size_t)row * Ncols + col] = val + bias[col];
                }
            }
        }
    }
}

// ---------------- V transpose: qkv v-slice -> vt[bh][64][NPAD], zero-padded ----------------
__global__ void __launch_bounds__(256) vtrans_kernel(
    const _Float16* __restrict__ qkv, _Float16* __restrict__ vt)
{
    __shared__ _Float16 Ts[64][72];
    const int nt = blockIdx.x;   // 0..17
    const int bh = blockIdx.y;   // 0..95
    const int b = bh / Hh, h = bh - b * Hh;
    const int n0 = nt * 64;
    const int tid = threadIdx.x;
    const _Float16* vsrc = qkv + (size_t)b * Nn * QKVC + 2 * DIMC + h * HD;
#pragma unroll
    for (int i = 0; i < 2; ++i) {
        int t = tid + i * 256;
        int r = t >> 3, cg = t & 7;
        int gn = n0 + r;
        f16x8 v8 = {};
        if (gn < Nn) v8 = *(const f16x8*)(vsrc + (size_t)gn * QKVC + cg * 8);
        *(f16x8*)&Ts[r][cg * 8] = v8;
    }
    __syncthreads();
#pragma unroll
    for (int i = 0; i < 2; ++i) {
        int t = tid + i * 256;
        int d = t >> 3, ng = t & 7;
        f16x8 o;
#pragma unroll
        for (int s = 0; s < 8; ++s) o[s] = Ts[ng * 8 + s][d];
        *(f16x8*)(vt + ((size_t)bh * HD + d) * NPAD + n0 + ng * 8) = o;
    }
}

// ---------------- RoPE-2D + scale-fold + cls row/col pre-dots ----------------
__global__ void __launch_bounds__(256) rope_kernel(
    _Float16* __restrict__ qkv, const int* __restrict__ xpos,
    float* __restrict__ col0, float* __restrict__ row0)
{
    int gw = blockIdx.x * 4 + (threadIdx.x >> 6);
    int lane = threadIdx.x & 63;
    if (gw >= Bb * Hh * Nn) return;
    int n = gw % Nn;
    int bh = gw / Nn;
    int b = bh / Hh, h = bh - b * Hh;

    _Float16* qp = qkv + ((size_t)b * Nn + n) * QKVC + h * HD;
    _Float16* kp = qp + DIMC;
    const _Float16* qp0 = qkv + (size_t)b * Nn * QKVC + h * HD;
    const _Float16* kp0 = qp0 + DIMC;

    float q = (float)qp[lane];
    float k = (float)kp[lane];
    float q0 = (float)qp0[lane];
    float k0 = (float)kp0[lane];

    float dcol = q * k0, drow = q0 * k;
#pragma unroll
    for (int off = 1; off < 64; off <<= 1) {
        dcol += __shfl_xor(dcol, off);
        drow += __shfl_xor(drow, off);
    }
    if (lane == 0) {
        col0[gw] = dcol * K1;   // pre-scaled: flash does p = exp2(value)
        row0[gw] = drow * K1;
    }

    if (n >= 1) {
        int py = xpos[((size_t)b * Nn + n) * 2 + 0];
        int px = xpos[((size_t)b * Nn + n) * 2 + 1];
        float pos = (lane < 32) ? (float)py : (float)px;
        int j = lane & 15;
        float inv = __expf(-0.28782313662f * (float)j);   // 100^(-j/16)
        float ang = pos * inv;
        float sv = __sinf(ang), cv = __cosf(ang);
        float qp_ = __shfl_xor(q, 16);
        float kp_ = __shfl_xor(k, 16);
        float sgn = (lane & 16) ? 1.0f : -1.0f;
        qp[lane] = (_Float16)((q * cv + sgn * qp_ * sv) * K1);   // scale folded into q
        kp[lane] = (_Float16)(k * cv + sgn * kp_ * sv);          // k unscaled
    }
}

// ---------------- flash attention: TRANSPOSED pipeline, no Ps buffer ----------------
// S^T = mfma(K_frag, Q_frag): lane holds (j = ct*16+quad*4+r, i = l16) -> all 32
// score values of a lane share Q-row i = l16. lrow is ONE scalar. P^T -> PV
// B-fragment via pkrtz pairs + 8 bpermute + 4 select per ks (no LDS round-trip).
// O^T = mfma(V_frag, P_frag): lane holds (d = ct*16+quad*4+r, i = l16) -> epilogue
// is 4x 8B stores, l needs only a 2-shfl quad reduce. LDS = Ks+Vt = 35.8 KB ->
// 4 blocks/CU if VGPR <= 128. Plain launch_bounds(256) (min-waves spilled, R2/R3).
// Fragment operands from LDS only (R6 lesson).
__global__ void __launch_bounds__(256) flash_kernel(
    const _Float16* __restrict__ qkv, const _Float16* __restrict__ vt,
    const float* __restrict__ col0, const float* __restrict__ row0,
    _Float16* __restrict__ att)
{
    __shared__ _Float16 Ks[128][72];
    __shared__ _Float16 Vt[64][136];

    const int qt = blockIdx.x, bh = blockIdx.y;
    const int b = bh / Hh, h = bh - b * Hh;
    const int tid = threadIdx.x, wid = tid >> 6, lane = tid & 63;
    const int quad = lane >> 4, l16 = lane & 15;
    const int q0row = qt * 64;
    const int c0base = bh * Nn;
    const _Float16* qg = qkv + (size_t)b * Nn * QKVC + h * HD;   // + n*QKVC + d
    const _Float16* kg = qg + DIMC;
    const _Float16* vtg = vt + (size_t)bh * HD * NPAD;

    // staging coordinates (fixed per thread)
    const int kR = tid >> 3, kC = (tid & 7) * 8;    // K: rows kR + i*32
    const int vD = tid >> 4, vC = (tid & 15) * 8;   // V: rows vD + i*16

    // stage Q tile into Ks rows 0..63 (scratch), hoist B-side fragments
#pragma unroll
    for (int i = 0; i < 2; ++i) {
        int t = tid + i * 256;
        int r = t >> 3, cg = t & 7;
        int gr = q0row + r;
        f16x8 v8 = {};
        if (gr < Nn) v8 = *(const f16x8*)(qg + (size_t)gr * QKVC + cg * 8);
        *(f16x8*)&Ks[r][cg * 8] = v8;
    }
    __syncthreads();
    f16x8 aq[2];
#pragma unroll
    for (int ks = 0; ks < 2; ++ks)
        aq[ks] = *(const f16x8*)&Ks[wid * 16 + l16][ks * 32 + quad * 8];
    __syncthreads();   // all waves read Q before chunk 0 overwrites Ks

    f32x4 oaccT[4] = {};          // O^T: d = ct*16+quad*4+r, i = l16
    float lrow = 0.f;             // per-lane partial sum over this lane's j-slots
    const int gi = q0row + wid * 16 + l16;   // this lane's Q token

    // gather-transpose constants
    const int src0 = (((2 * quad) & 3) << 4) + l16;       // jj 0..3 source lane
    const int src1 = (((2 * quad + 1) & 3) << 4) + l16;   // jj 4..7 source lane
    const bool hi = (quad >= 2);                          // ct_s = 2ks + (quad>>1)

    // prefetch chunk 0 into registers
    f16x8 kreg[4], vreg[4];
#pragma unroll
    for (int i = 0; i < 4; ++i) {
        int gr = kR + i * 32;
        f16x8 v8 = {};
        if (gr < Nn) v8 = *(const f16x8*)(kg + (size_t)gr * QKVC + kC);
        kreg[i] = v8;
        vreg[i] = *(const f16x8*)(vtg + (size_t)(vD + i * 16) * NPAD + vC);
    }

    for (int c0 = 0; c0 < Nn; c0 += 128) {
        // commit prefetched registers to LDS
#pragma unroll
        for (int i = 0; i < 4; ++i) {
            *(f16x8*)&Ks[kR + i * 32][kC] = kreg[i];
            *(f16x8*)&Vt[vD + i * 16][vC] = vreg[i];
        }
        __syncthreads();

        // prefetch next chunk (VMEM overlapped with compute below)
        int cn = c0 + 128;
        if (cn < Nn) {
#pragma unroll
            for (int i = 0; i < 4; ++i) {
                int gr = cn + kR + i * 32;
                f16x8 v8 = {};
                if (gr < Nn) v8 = *(const f16x8*)(kg + (size_t)gr * QKVC + kC);
                kreg[i] = v8;
                vreg[i] = *(const f16x8*)(vtg + (size_t)(vD + i * 16) * NPAD + cn + vC);
            }
        }

        // S^T = K Q^T  (A = K tokens, B = Q rows; scale pre-folded into Q)
        f32x4 sacc[8] = {};
#pragma unroll
        for (int ks = 0; ks < 2; ++ks)
#pragma unroll
            for (int ct = 0; ct < 8; ++ct) {
                f16x8 ak = *(const f16x8*)&Ks[ct * 16 + l16][ks * 32 + quad * 8];
                sacc[ct] = __builtin_amdgcn_mfma_f32_16x16x32_f16(ak, aq[ks], sacc[ct], 0, 0, 0);
            }

        // cls column (j==0): lane's i = l16; element (ct=0, r=0) on quad 0
        if (c0 == 0 && quad == 0)
            sacc[0][0] = col0[c0base + (gi < Nn ? gi : 0)];
        // cls row (i==0): l16==0 lanes of first q-tile's wave 0
        if (q0row == 0 && wid == 0 && l16 == 0) {
#pragma unroll
            for (int ct = 0; ct < 8; ++ct)
#pragma unroll
                for (int r = 0; r < 4; ++r) {
                    int gj = c0 + ct * 16 + quad * 4 + r;
                    if (gj < Nn) sacc[ct][r] = row0[c0base + gj];
                }
        }

        // p = 2^s'; per-lane sum; pack f16 pairs (r01, r23) for the gather
        int pkl[8], pkh[8];
#pragma unroll
        for (int ct = 0; ct < 8; ++ct) {
            float p0 = exp2f(sacc[ct][0]);
            float p1 = exp2f(sacc[ct][1]);
            float p2 = exp2f(sacc[ct][2]);
            float p3 = exp2f(sacc[ct][3]);
            lrow += (p0 + p1) + (p2 + p3);
            pkl[ct] = __builtin_bit_cast(int, __builtin_amdgcn_cvt_pkrtz(p0, p1));
            pkh[ct] = __builtin_bit_cast(int, __builtin_amdgcn_cvt_pkrtz(p2, p3));
        }

        // O^T += V^T P^T : assemble P B-frag by cross-lane gather, V from LDS
#pragma unroll
        for (int ks = 0; ks < 4; ++ks) {
            int a0 = __shfl(pkl[2 * ks], src0), b0 = __shfl(pkl[2 * ks + 1], src0);
            int a1 = __shfl(pkh[2 * ks], src0), b1 = __shfl(pkh[2 * ks + 1], src0);
            int a2 = __shfl(pkl[2 * ks], src1), b2 = __shfl(pkl[2 * ks + 1], src1);
            int a3 = __shfl(pkh[2 * ks], src1), b3 = __shfl(pkh[2 * ks + 1], src1);
            i32x4 wi;
            wi.x = hi ? b0 : a0;
            wi.y = hi ? b1 : a1;
            wi.z = hi ? b2 : a2;
            wi.w = hi ? b3 : a3;
            f16x8 bp = __builtin_bit_cast(f16x8, wi);
#pragma unroll
            for (int ct = 0; ct < 4; ++ct) {
                f16x8 av = *(const f16x8*)&Vt[ct * 16 + l16][ks * 32 + quad * 8];
                oaccT[ct] = __builtin_amdgcn_mfma_f32_16x16x32_f16(av, bp, oaccT[ct], 0, 0, 0);
            }
        }
        __syncthreads();   // Ks/Vt consumed before next chunk's commit
    }

    // epilogue: reduce l over quads, subtract pad count, store O^T rows
    float l = lrow;
    l += __shfl_xor(l, 16);
    l += __shfl_xor(l, 32);
    l -= PADCNT;
    if (gi < Nn) {
        float inv_l = 1.0f / l;
        _Float16* dst = att + ((size_t)b * Nn + gi) * DIMC + h * HD;
#pragma unroll
        for (int ct = 0; ct < 4; ++ct) {
            f16x4 o4;
#pragma unroll
            for (int r = 0; r < 4; ++r) o4[r] = (_Float16)(oaccT[ct][r] * inv_l);
            *(f16x4*)(dst + ct * 16 + quad * 4) = o4;
        }
    }
}

extern "C" void kernel_launch(void* const* d_in, const int* in_sizes, int n_in,
                              void* d_out, int out_size, void* d_ws, size_t ws_size,
                              hipStream_t stream) {
    const float* x      = (const float*)d_in[1];
    const int*   xpos   = (const int*)d_in[2];
    const float* w_qkv  = (const float*)d_in[4];
    const float* w_proj = (const float*)d_in[5];
    const float* b_proj = (const float*)d_in[6];
    float* out = (float*)d_out;

    char* ws = (char*)d_ws;
    size_t off = 0;
    auto alloc = [&](size_t bytes) {
        char* p = ws + off;
        off += (bytes + 255) & ~(size_t)255;
        return p;
    };
    _Float16* xh     = (_Float16*)alloc((size_t)MPADA * DIMC * 2);   // padded rows for unguarded staging
    _Float16* qkvh   = (_Float16*)alloc((size_t)MROWS * QKVC * 2);
    _Float16* vt     = (_Float16*)alloc((size_t)Bb * Hh * HD * NPAD * 2);
    _Float16* wqkvh  = (_Float16*)alloc((size_t)3 * DIMC * DIMC * 2);
    _Float16* wprojh = (_Float16*)alloc((size_t)DIMC * DIMC * 2);
    float* col0      = (float*)alloc((size_t)Bb * Hh * Nn * 4);
    float* row0      = (float*)alloc((size_t)Bb * Hh * Nn * 4);
    _Float16* atth   = xh;  // alias: x consumed by QKV GEMM before flash writes att

    {
        int n0 = (MROWS * DIMC) / 4;
        int n1 = (3 * DIMC * DIMC) / 4;
        int n2 = (DIMC * DIMC) / 4;
        int nt = n0 + n1 + n2;
        cvt3_kernel<<<(nt + 255) / 256, 256, 0, stream>>>(
            x, xh, n0, w_qkv, wqkvh, n1, w_proj, wprojh, n2);
    }

    // QKV projection -> packed [b,n,3,h,d] (natural GEMM C layout)
    gemm_kernel<0><<<dim3(MPADA / 128, QKVC / 128), 256, 0, stream>>>(
        xh, wqkvh, MROWS, QKVC, DIMC, qkvh, nullptr, nullptr);

    rope_kernel<<<(Bb * Hh * Nn) / 4, 256, 0, stream>>>(qkvh, xpos, col0, row0);

    vtrans_kernel<<<dim3(NPAD / 64, Bb * Hh), 256, 0, stream>>>(qkvh, vt);

    flash_kernel<<<dim3((Nn + 63) / 64, Bb * Hh), 256, 0, stream>>>(
        qkvh, vt, col0, row0, atth);

    gemm_kernel<1><<<dim3(MPADA / 128, DIMC / 128), 256, 0, stream>>>(
        atth, wprojh, MROWS, DIMC, DIMC, nullptr, b_proj, out);
}

// Round 11
// 296.024 us; speedup vs baseline: 1.0446x; 1.0446x over previous
//
#include <hip/hip_runtime.h>

#define Bb 8
#define Nn 1025
#define Hh 12
#define HD 64
#define DIMC 768
#define QKVC 2304          // 3*DIMC, token stride of packed qkv
#define MROWS (Bb * Nn)    // 8200
#define MPADA 8320         // 65*128, padded A rows for unguarded global_load_lds staging
#define NPAD 1152          // 18*64, zero-padded token dim for transposed V
#define K1 0.180336880111f // 0.125 * log2(e) — folded into q by rope kernel
#define PADCNT 127.0f      // pad tokens, each contributing p=2^0=1 to l
#define RBLK ((Bb * Hh * Nn + 3) / 4)   // rope BLOCKS: 98400 waves / 4 waves-per-block = 24600

typedef _Float16 f16x8 __attribute__((ext_vector_type(8)));
typedef _Float16 f16x4 __attribute__((ext_vector_type(4)));
typedef float f32x4 __attribute__((ext_vector_type(4)));

typedef const __attribute__((address_space(1))) void gv_t;
typedef __attribute__((address_space(3))) void lv_t;

// ---------------- fused fp32 -> fp16 convert for 3 tensors ----------------
__global__ void cvt3_kernel(const float* __restrict__ s0, _Float16* __restrict__ d0, int n0,
                            const float* __restrict__ s1, _Float16* __restrict__ d1, int n1,
                            const float* __restrict__ s2, _Float16* __restrict__ d2, int n2) {
    int i = blockIdx.x * 256 + threadIdx.x;
    const float* s; _Float16* d; int j;
    if (i < n0)           { s = s0; d = d0; j = i; }
    else if (i < n0 + n1) { s = s1; d = d1; j = i - n0; }
    else if (i < n0 + n1 + n2) { s = s2; d = d2; j = i - n0 - n1; }
    else return;
    float4 v = ((const float4*)s)[j];
    f16x4 h;
    h.x = (_Float16)v.x; h.y = (_Float16)v.y; h.z = (_Float16)v.z; h.w = (_Float16)v.w;
    ((f16x4*)d)[j] = h;
}

// ---------------- MFMA GEMM, global_load_lds staging, 2xBK=32 per barrier ----------------
template <int MODE>
__global__ void __launch_bounds__(256) gemm_kernel(
    const _Float16* __restrict__ A, const _Float16* __restrict__ W,
    int M, int Ncols, int K,
    _Float16* __restrict__ outh, const float* __restrict__ bias, float* __restrict__ outf)
{
    __shared__ _Float16 As[2][128 * 32];
    __shared__ _Float16 Ws[2][128 * 32];
    const int tid = threadIdx.x;
    const int wid = tid >> 6, lane = tid & 63;
    const int quad = lane >> 4, l16 = lane & 15;
    const int bm = blockIdx.x * 128, bn = blockIdx.y * 128;
    const int wm = (wid >> 1) * 64, wn = (wid & 1) * 64;

    f32x4 acc[4][4] = {};

    for (int kk = 0; kk < K; kk += 64) {
#pragma unroll
        for (int half = 0; half < 2; ++half) {
#pragma unroll
            for (int c = 0; c < 2; ++c) {
                int s = c * 256 + tid;
                int row = s >> 2, gr = s & 3;
                const _Float16* ga = A + (size_t)(bm + row) * K + kk + half * 32 + gr * 8;
                const _Float16* gw = W + (size_t)(bn + row) * K + kk + half * 32 + gr * 8;
                _Float16* la = As[half] + (size_t)(c * 256 + wid * 64) * 8;
                _Float16* lw = Ws[half] + (size_t)(c * 256 + wid * 64) * 8;
                __builtin_amdgcn_global_load_lds((gv_t*)ga, (lv_t*)la, 16, 0, 0);
                __builtin_amdgcn_global_load_lds((gv_t*)gw, (lv_t*)lw, 16, 0, 0);
            }
        }
        __syncthreads();

#pragma unroll
        for (int half = 0; half < 2; ++half) {
            f16x8 af[4], bf[4];
#pragma unroll
            for (int t = 0; t < 4; ++t) {
                af[t] = *(const f16x8*)(As[half] + (size_t)(wm + t * 16 + l16) * 32 + quad * 8);
                bf[t] = *(const f16x8*)(Ws[half] + (size_t)(wn + t * 16 + l16) * 32 + quad * 8);
            }
#pragma unroll
            for (int tm = 0; tm < 4; ++tm)
#pragma unroll
                for (int tn = 0; tn < 4; ++tn)
                    acc[tm][tn] = __builtin_amdgcn_mfma_f32_16x16x32_f16(af[tm], bf[tn], acc[tm][tn], 0, 0, 0);
        }
        __syncthreads();
    }

#pragma unroll
    for (int tm = 0; tm < 4; ++tm) {
#pragma unroll
        for (int r = 0; r < 4; ++r) {
            int row = bm + wm + tm * 16 + quad * 4 + r;
            if (row >= M) continue;
#pragma unroll
            for (int tn = 0; tn < 4; ++tn) {
                int col = bn + wn + tn * 16 + l16;
                float val = acc[tm][tn][r];
                if (MODE == 0) {
                    outh[(size_t)row * Ncols + col] = (_Float16)val;
                } else {
                    outf[(size_t)row * Ncols + col] = val + bias[col];
                }
            }
        }
    }
}

// ---------------- fused RoPE-2D (+scale-fold, cls dots) and V-transpose ----------------
// Blocks [0, RBLK): rope on q/k slices (4 waves/block, one (b,h,n) each).
// Blocks [RBLK, RBLK+1728): vtrans on v slice. Disjoint data -> safe to fuse.
__global__ void __launch_bounds__(256) ropevtrans_kernel(
    _Float16* __restrict__ qkv, const int* __restrict__ xpos,
    float* __restrict__ col0, float* __restrict__ row0, _Float16* __restrict__ vt)
{
    __shared__ _Float16 Ts[64][72];
    const int blk = blockIdx.x;
    const int tid = threadIdx.x;

    if (blk < RBLK) {
        // ---- rope part: one wave per (b,h,n) ----
        int gw = blk * 4 + (tid >> 6);
        int lane = tid & 63;
        if (gw >= Bb * Hh * Nn) return;
        int n = gw % Nn;
        int bh = gw / Nn;
        int b = bh / Hh, h = bh - b * Hh;

        _Float16* qp = qkv + ((size_t)b * Nn + n) * QKVC + h * HD;
        _Float16* kp = qp + DIMC;
        const _Float16* qp0 = qkv + (size_t)b * Nn * QKVC + h * HD;
        const _Float16* kp0 = qp0 + DIMC;

        float q = (float)qp[lane];
        float k = (float)kp[lane];
        float q0 = (float)qp0[lane];
        float k0 = (float)kp0[lane];

        float dcol = q * k0, drow = q0 * k;
#pragma unroll
        for (int off = 1; off < 64; off <<= 1) {
            dcol += __shfl_xor(dcol, off);
            drow += __shfl_xor(drow, off);
        }
        if (lane == 0) {
            col0[gw] = dcol * K1;   // pre-scaled: flash does p = exp2(value)
            row0[gw] = drow * K1;
        }

        if (n >= 1) {
            int py = xpos[((size_t)b * Nn + n) * 2 + 0];
            int px = xpos[((size_t)b * Nn + n) * 2 + 1];
            float pos = (lane < 32) ? (float)py : (float)px;
            int j = lane & 15;
            float inv = __expf(-0.28782313662f * (float)j);   // 100^(-j/16)
            float ang = pos * inv;
            float sv = __sinf(ang), cv = __cosf(ang);
            float qp_ = __shfl_xor(q, 16);
            float kp_ = __shfl_xor(k, 16);
            float sgn = (lane & 16) ? 1.0f : -1.0f;
            qp[lane] = (_Float16)((q * cv + sgn * qp_ * sv) * K1);   // scale folded into q
            kp[lane] = (_Float16)(k * cv + sgn * kp_ * sv);          // k unscaled
        }
    } else {
        // ---- vtrans part: qkv v-slice -> vt[bh][64][NPAD], zero-padded ----
        int idx = blk - RBLK;
        int nt = idx % (NPAD / 64);
        int bh = idx / (NPAD / 64);
        int b = bh / Hh, h = bh - b * Hh;
        int n0 = nt * 64;
        const _Float16* vsrc = qkv + (size_t)b * Nn * QKVC + 2 * DIMC + h * HD;
#pragma unroll
        for (int i = 0; i < 2; ++i) {
            int t = tid + i * 256;
            int r = t >> 3, cg = t & 7;
            int gn = n0 + r;
            f16x8 v8 = {};
            if (gn < Nn) v8 = *(const f16x8*)(vsrc + (size_t)gn * QKVC + cg * 8);
            *(f16x8*)&Ts[r][cg * 8] = v8;
        }
        __syncthreads();
#pragma unroll
        for (int i = 0; i < 2; ++i) {
            int t = tid + i * 256;
            int d = t >> 3, ng = t & 7;
            f16x8 o;
#pragma unroll
            for (int s = 0; s < 8; ++s) o[s] = Ts[ng * 8 + s][d];
            *(f16x8*)(vt + ((size_t)bh * HD + d) * NPAD + n0 + ng * 8) = o;
        }
    }
}

// ---------------- flash attention: R8 structure (proven 91 us) ----------------
// BQ=64 (16 rows/wave), KV chunk 128, reg-prefetch staging, p = exp2(s') with
// scale folded into q, no OOB mask (pad K rows zero -> p=1, l corrected by
// -PADCNT). Ps wave-private -> 2 barriers/chunk. Fragment operands from LDS only
// (R6: global-direct operands latency-bound; R9: bpermute gather uses the same
// LDS pipe and regressed). Plain launch_bounds(256) (min-waves spilled, R2/R3).
__global__ void __launch_bounds__(256) flash_kernel(
    const _Float16* __restrict__ qkv, const _Float16* __restrict__ vt,
    const float* __restrict__ col0, const float* __restrict__ row0,
    _Float16* __restrict__ att)
{
    __shared__ _Float16 Ks[128][72];
    __shared__ _Float16 Vt[64][136];
    __shared__ _Float16 Ps[64][136];   // wave-private rows

    const int qt = blockIdx.x, bh = blockIdx.y;
    const int b = bh / Hh, h = bh - b * Hh;
    const int tid = threadIdx.x, wid = tid >> 6, lane = tid & 63;
    const int quad = lane >> 4, l16 = lane & 15;
    const int q0row = qt * 64;
    const int c0base = bh * Nn;
    const _Float16* qg = qkv + (size_t)b * Nn * QKVC + h * HD;   // + n*QKVC + d
    const _Float16* kg = qg + DIMC;
    const _Float16* vtg = vt + (size_t)bh * HD * NPAD;

    // staging coordinates (fixed per thread)
    const int kR = tid >> 3, kC = (tid & 7) * 8;    // K: rows kR + i*32
    const int vD = tid >> 4, vC = (tid & 15) * 8;   // V: rows vD + i*16

    // stage Q tile into Ks rows 0..63, hoist fragments, release the buffer
#pragma unroll
    for (int i = 0; i < 2; ++i) {
        int t = tid + i * 256;
        int r = t >> 3, cg = t & 7;
        int gr = q0row + r;
        f16x8 v8 = {};
        if (gr < Nn) v8 = *(const f16x8*)(qg + (size_t)gr * QKVC + cg * 8);
        *(f16x8*)&Ks[r][cg * 8] = v8;
    }
    __syncthreads();
    f16x8 aq[2];
#pragma unroll
    for (int ks = 0; ks < 2; ++ks)
        aq[ks] = *(const f16x8*)&Ks[wid * 16 + l16][ks * 32 + quad * 8];
    __syncthreads();

    f32x4 oacc[4] = {};
    float lrow[4] = {0.f, 0.f, 0.f, 0.f};
    const int gibase = q0row + wid * 16 + quad * 4;

    // prefetch chunk 0 into registers
    f16x8 kreg[4], vreg[4];
#pragma unroll
    for (int i = 0; i < 4; ++i) {
        int gr = kR + i * 32;
        f16x8 v8 = {};
        if (gr < Nn) v8 = *(const f16x8*)(kg + (size_t)gr * QKVC + kC);
        kreg[i] = v8;
        vreg[i] = *(const f16x8*)(vtg + (size_t)(vD + i * 16) * NPAD + vC);
    }

    for (int c0 = 0; c0 < Nn; c0 += 128) {
        // commit prefetched registers to LDS
#pragma unroll
        for (int i = 0; i < 4; ++i) {
            *(f16x8*)&Ks[kR + i * 32][kC] = kreg[i];
            *(f16x8*)&Vt[vD + i * 16][vC] = vreg[i];
        }
        __syncthreads();

        // prefetch next chunk (VMEM overlapped with compute below)
        int cn = c0 + 128;
        if (cn < Nn) {
#pragma unroll
            for (int i = 0; i < 4; ++i) {
                int gr = cn + kR + i * 32;
                f16x8 v8 = {};
                if (gr < Nn) v8 = *(const f16x8*)(kg + (size_t)gr * QKVC + kC);
                kreg[i] = v8;
                vreg[i] = *(const f16x8*)(vtg + (size_t)(vD + i * 16) * NPAD + cn + vC);
            }
        }

        // S' = Q' K^T  (scale already folded into Q)
        f32x4 sacc[8] = {};
#pragma unroll
        for (int ks = 0; ks < 2; ++ks)
#pragma unroll
            for (int ct = 0; ct < 8; ++ct) {
                f16x8 bk = *(const f16x8*)&Ks[ct * 16 + l16][ks * 32 + quad * 8];
                sacc[ct] = __builtin_amdgcn_mfma_f32_16x16x32_f16(aq[ks], bk, sacc[ct], 0, 0, 0);
            }

        // cls column (gj==0): only chunk 0
        if (c0 == 0 && l16 == 0) {
#pragma unroll
            for (int r = 0; r < 4; ++r) {
                int gi = gibase + r;
                sacc[0][r] = col0[c0base + (gi < Nn ? gi : 0)];
            }
        }
        // cls row (gi==0): only first q-tile, wave 0, quad 0
        if (q0row == 0 && wid == 0 && quad == 0) {
#pragma unroll
            for (int ct = 0; ct < 8; ++ct) {
                int gj = c0 + ct * 16 + l16;
                if (gj < Nn) sacc[ct][0] = row0[c0base + gj];
            }
        }

        // p = 2^s'; partial row sums; stage to Ps (f16). Pad cols: p=1,
        // harmless for O (V pads zero), corrected in l by -PADCNT at the end.
#pragma unroll
        for (int ct = 0; ct < 8; ++ct) {
#pragma unroll
            for (int r = 0; r < 4; ++r) {
                float p = exp2f(sacc[ct][r]);
                lrow[r] += p;
                Ps[wid * 16 + quad * 4 + r][ct * 16 + l16] = (_Float16)p;
            }
        }

        // O += P @ V  (own Ps rows + shared Vt, all from LDS)
#pragma unroll
        for (int ks = 0; ks < 4; ++ks) {
            f16x8 ap = *(const f16x8*)&Ps[wid * 16 + l16][ks * 32 + quad * 8];
#pragma unroll
            for (int ct = 0; ct < 4; ++ct) {
                f16x8 bv = *(const f16x8*)&Vt[ct * 16 + l16][ks * 32 + quad * 8];
                oacc[ct] = __builtin_amdgcn_mfma_f32_16x16x32_f16(ap, bv, oacc[ct], 0, 0, 0);
            }
        }
        __syncthreads();   // Ks/Vt consumed before next chunk's commit
    }

    // epilogue: 16-lane reduce of l, subtract pad contribution, store att
#pragma unroll
    for (int r = 0; r < 4; ++r) {
        float l = lrow[r];
#pragma unroll
        for (int off = 1; off < 16; off <<= 1) l += __shfl_xor(l, off);
        l -= PADCNT;
        int gi = q0row + wid * 16 + quad * 4 + r;
        if (gi >= Nn) continue;
        float inv_l = 1.0f / l;
#pragma unroll
        for (int ct = 0; ct < 4; ++ct) {
            att[((size_t)b * Nn + gi) * DIMC + h * HD + ct * 16 + l16] =
                (_Float16)(oacc[ct][r] * inv_l);
        }
    }
}

extern "C" void kernel_launch(void* const* d_in, const int* in_sizes, int n_in,
                              void* d_out, int out_size, void* d_ws, size_t ws_size,
                              hipStream_t stream) {
    const float* x      = (const float*)d_in[1];
    const int*   xpos   = (const int*)d_in[2];
    const float* w_qkv  = (const float*)d_in[4];
    const float* w_proj = (const float*)d_in[5];
    const float* b_proj = (const float*)d_in[6];
    float* out = (float*)d_out;

    char* ws = (char*)d_ws;
    size_t off = 0;
    auto alloc = [&](size_t bytes) {
        char* p = ws + off;
        off += (bytes + 255) & ~(size_t)255;
        return p;
    };
    _Float16* xh     = (_Float16*)alloc((size_t)MPADA * DIMC * 2);   // padded rows for unguarded staging
    _Float16* qkvh   = (_Float16*)alloc((size_t)MROWS * QKVC * 2);
    _Float16* vt     = (_Float16*)alloc((size_t)Bb * Hh * HD * NPAD * 2);
    _Float16* wqkvh  = (_Float16*)alloc((size_t)3 * DIMC * DIMC * 2);
    _Float16* wprojh = (_Float16*)alloc((size_t)DIMC * DIMC * 2);
    float* col0      = (float*)alloc((size_t)Bb * Hh * Nn * 4);
    float* row0      = (float*)alloc((size_t)Bb * Hh * Nn * 4);
    _Float16* atth   = xh;  // alias: x consumed by QKV GEMM before flash writes att

    {
        int n0 = (MROWS * DIMC) / 4;
        int n1 = (3 * DIMC * DIMC) / 4;
        int n2 = (DIMC * DIMC) / 4;
        int nt = n0 + n1 + n2;
        cvt3_kernel<<<(nt + 255) / 256, 256, 0, stream>>>(
            x, xh, n0, w_qkv, wqkvh, n1, w_proj, wprojh, n2);
    }

    // QKV projection -> packed [b,n,3,h,d] (natural GEMM C layout)
    gemm_kernel<0><<<dim3(MPADA / 128, QKVC / 128), 256, 0, stream>>>(
        xh, wqkvh, MROWS, QKVC, DIMC, qkvh, nullptr, nullptr);

    // fused rope (q/k) + V transpose
    ropevtrans_kernel<<<RBLK + (NPAD / 64) * Bb * Hh, 256, 0, stream>>>(
        qkvh, xpos, col0, row0, vt);

    flash_kernel<<<dim3((Nn + 63) / 64, Bb * Hh), 256, 0, stream>>>(
        qkvh, vt, col0, row0, atth);

    gemm_kernel<1><<<dim3(MPADA / 128, DIMC / 128), 256, 0, stream>>>(
        atth, wprojh, MROWS, DIMC, DIMC, nullptr, b_proj, out);
}